// Round 1
// baseline (575.196 us; speedup 1.0000x reference)
//
#include <hip/hip_runtime.h>
#include <hip/hip_bf16.h>

// Causal GQA flash-attention forward, fp32 in/out, bf16 MFMA compute.
// q: [2,32,2048,128], k/v: [2,8,2048,128] (rep=4), out: [2,32,2048,128].

typedef __bf16 bf16x8 __attribute__((ext_vector_type(8)));
typedef float f32x4 __attribute__((ext_vector_type(4)));

constexpr int B_ = 2, HQ = 32, HK = 8;
constexpr int SQ = 2048, SK = 2048, D = 128;
constexpr int QT = 64;   // q rows per block (16 per wave x 4 waves)
constexpr int KT = 32;   // kv rows per tile

__device__ __forceinline__ __bf16 f2bf(float f) {
  // round-to-nearest-even f32 -> bf16
  unsigned u = __float_as_uint(f);
  u += 0x7fffu + ((u >> 16) & 1u);
  unsigned short hs = (unsigned short)(u >> 16);
  __bf16 b;
  __builtin_memcpy(&b, &hs, 2);
  return b;
}

__global__ __launch_bounds__(256, 3)
void fa_fwd(const float* __restrict__ qg_, const float* __restrict__ kg_,
            const float* __restrict__ vg_, float* __restrict__ og_)
{
  // LDS: K row-major [32][128+8] (pad 16B keeps b128 alignment, 2-way banks)
  //      V transposed [128][32+8] so PV B-frags are contiguous b128 reads
  //      P per-wave [16][32+8] to re-layout softmax output into A-frags
  __shared__ __bf16 Kl[KT][D + 8];
  __shared__ __bf16 Vt[D][KT + 8];
  __shared__ __bf16 Pl[4][16][KT + 8];

  const int qt = (int)gridDim.x - 1 - (int)blockIdx.x;  // heavy tiles first
  const int bh = blockIdx.y;
  const int b  = bh >> 5;
  const int h  = bh & 31;
  const int hk = h >> 2;          // GQA: repeat_interleave, rep = 4

  const int tid  = threadIdx.x;
  const int wave = tid >> 6;
  const int lane = tid & 63;
  const int lg   = lane >> 4;     // 0..3
  const int ln   = lane & 15;     // 0..15

  const int q0 = qt * QT;
  const int qw = q0 + wave * 16;  // this wave's q-row base

  const float* qg = qg_ + ((size_t)(b * HQ + h) * SQ + qw) * D;
  const float* kg = kg_ + (size_t)(b * HK + hk) * SK * D;
  const float* vg = vg_ + (size_t)(b * HK + hk) * SK * D;
  float*       og = og_ + ((size_t)(b * HQ + h) * SQ + qw) * D;

  const float scale = 0.08838834764831845f;  // 1/sqrt(128)

  // Q fragments: A[m=ln][k = 32c + 8*lg + j], scale folded in.
  bf16x8 qf[4];
#pragma unroll
  for (int c = 0; c < 4; ++c) {
    const float* p = qg + (size_t)ln * D + 32 * c + 8 * lg;
    const float4 x0 = *(const float4*)(p);
    const float4 x1 = *(const float4*)(p + 4);
    bf16x8 t;
    t[0] = f2bf(x0.x * scale); t[1] = f2bf(x0.y * scale);
    t[2] = f2bf(x0.z * scale); t[3] = f2bf(x0.w * scale);
    t[4] = f2bf(x1.x * scale); t[5] = f2bf(x1.y * scale);
    t[6] = f2bf(x1.z * scale); t[7] = f2bf(x1.w * scale);
    qf[c] = t;
  }

  f32x4 oacc[8];
#pragma unroll
  for (int dc = 0; dc < 8; ++dc) oacc[dc] = (f32x4){0.f, 0.f, 0.f, 0.f};
  float m[4] = {-1e30f, -1e30f, -1e30f, -1e30f};
  float l[4] = {0.f, 0.f, 0.f, 0.f};

  const int kv_end = q0 + QT;      // causal: keys < q0+64 suffice for this block

  // staging assignments
  const int srow = tid >> 3;       // K: row 0..31
  const int scol = (tid & 7) * 16; // K: 16-col chunk
  const int vd   = tid >> 1;       // V^T: d row 0..127
  const int vk0  = (tid & 1) * 16; // V^T: k offset 0/16

  for (int kb = 0; kb < kv_end; kb += KT) {
    __syncthreads();  // previous tile's LDS reads complete

    // --- stage K tile (coalesced float4 reads, b128 LDS writes) ---
    {
      const float* src = kg + (size_t)(kb + srow) * D + scol;
      const float4 a0 = *(const float4*)(src);
      const float4 a1 = *(const float4*)(src + 4);
      const float4 a2 = *(const float4*)(src + 8);
      const float4 a3 = *(const float4*)(src + 12);
      bf16x8 w0, w1;
      w0[0]=f2bf(a0.x); w0[1]=f2bf(a0.y); w0[2]=f2bf(a0.z); w0[3]=f2bf(a0.w);
      w0[4]=f2bf(a1.x); w0[5]=f2bf(a1.y); w0[6]=f2bf(a1.z); w0[7]=f2bf(a1.w);
      w1[0]=f2bf(a2.x); w1[1]=f2bf(a2.y); w1[2]=f2bf(a2.z); w1[3]=f2bf(a2.w);
      w1[4]=f2bf(a3.x); w1[5]=f2bf(a3.y); w1[6]=f2bf(a3.z); w1[7]=f2bf(a3.w);
      *(bf16x8*)&Kl[srow][scol]     = w0;
      *(bf16x8*)&Kl[srow][scol + 8] = w1;
    }
    // --- stage V^T tile (strided dword reads hit L1/L2; contiguous writes) ---
    {
      const float* src = vg + (size_t)(kb + vk0) * D + vd;
      bf16x8 w0, w1;
#pragma unroll
      for (int i = 0; i < 8; ++i) w0[i] = f2bf(src[(size_t)i * D]);
#pragma unroll
      for (int i = 0; i < 8; ++i) w1[i] = f2bf(src[(size_t)(i + 8) * D]);
      *(bf16x8*)&Vt[vd][vk0]     = w0;
      *(bf16x8*)&Vt[vd][vk0 + 8] = w1;
    }
    __syncthreads();

    // --- S = (Q*scale) K^T : two 16-key halves ---
    f32x4 s0 = {0.f, 0.f, 0.f, 0.f}, s1 = {0.f, 0.f, 0.f, 0.f};
#pragma unroll
    for (int c = 0; c < 4; ++c) {
      const bf16x8 k0 = *(const bf16x8*)&Kl[ln][32 * c + 8 * lg];
      const bf16x8 k1 = *(const bf16x8*)&Kl[ln + 16][32 * c + 8 * lg];
      s0 = __builtin_amdgcn_mfma_f32_16x16x32_bf16(qf[c], k0, s0, 0, 0, 0);
      s1 = __builtin_amdgcn_mfma_f32_16x16x32_bf16(qf[c], k1, s1, 0, 0, 0);
    }

    // lane holds S[qrow = qw + 4*lg + r][key = kb + ln (+16 for s1)]
    const int qrow = qw + 4 * lg;
#pragma unroll
    for (int r = 0; r < 4; ++r) {
      if (kb + ln > qrow + r)      s0[r] = -1e30f;
      if (kb + 16 + ln > qrow + r) s1[r] = -1e30f;
    }

    // --- online softmax (row spread over 16 lanes of this lane-group) ---
    float tm[4], ts[4], p0[4], p1[4];
#pragma unroll
    for (int r = 0; r < 4; ++r) tm[r] = fmaxf(s0[r], s1[r]);
#pragma unroll
    for (int off = 1; off < 16; off <<= 1) {
#pragma unroll
      for (int r = 0; r < 4; ++r)
        tm[r] = fmaxf(tm[r], __shfl_xor(tm[r], off, 16));
    }
#pragma unroll
    for (int r = 0; r < 4; ++r) {
      const float mn   = fmaxf(m[r], tm[r]);
      const float corr = __expf(m[r] - mn);   // first tile: exp(-1e30)=0
      m[r] = mn;
      l[r] *= corr;
#pragma unroll
      for (int dc = 0; dc < 8; ++dc) oacc[dc][r] *= corr;
      p0[r] = __expf(s0[r] - mn);             // masked: exp(-huge)=0
      p1[r] = __expf(s1[r] - mn);
      ts[r] = p0[r] + p1[r];
    }
#pragma unroll
    for (int off = 1; off < 16; off <<= 1) {
#pragma unroll
      for (int r = 0; r < 4; ++r) ts[r] += __shfl_xor(ts[r], off, 16);
    }
#pragma unroll
    for (int r = 0; r < 4; ++r) l[r] += ts[r];

    // --- P -> per-wave LDS tile (re-layout for PV A-operand) ---
#pragma unroll
    for (int r = 0; r < 4; ++r) {
      Pl[wave][4 * lg + r][ln]      = f2bf(p0[r]);
      Pl[wave][4 * lg + r][16 + ln] = f2bf(p1[r]);
    }

    // --- O += P V  (A = P[m=ln][k=8lg+j], B = V[k][n] from V^T rows) ---
    const bf16x8 pf = *(const bf16x8*)&Pl[wave][ln][8 * lg];
#pragma unroll
    for (int dc = 0; dc < 8; ++dc) {
      const bf16x8 vf = *(const bf16x8*)&Vt[dc * 16 + ln][8 * lg];
      oacc[dc] = __builtin_amdgcn_mfma_f32_16x16x32_bf16(pf, vf, oacc[dc], 0, 0, 0);
    }
  }

  // --- epilogue: normalize and store fp32 ---
#pragma unroll
  for (int r = 0; r < 4; ++r) {
    const float inv = 1.f / l[r];
#pragma unroll
    for (int dc = 0; dc < 8; ++dc) {
      og[(size_t)(4 * lg + r) * D + dc * 16 + ln] = oacc[dc][r] * inv;
    }
  }
}

extern "C" void kernel_launch(void* const* d_in, const int* in_sizes, int n_in,
                              void* d_out, int out_size, void* d_ws, size_t ws_size,
                              hipStream_t stream) {
  const float* q = (const float*)d_in[0];
  const float* k = (const float*)d_in[1];
  const float* v = (const float*)d_in[2];
  float* out = (float*)d_out;
  dim3 grid(SQ / QT, B_ * HQ);   // 32 q-tiles x 64 batch-heads
  fa_fwd<<<grid, 256, 0, stream>>>(q, k, v, out);
}

// Round 2
// 247.867 us; speedup vs baseline: 2.3206x; 2.3206x over previous
//
#include <hip/hip_runtime.h>

// Causal GQA flash-attention fwd, fp32 I/O, bf16 32x32x16 MFMA, swapped-operand
// structure (S^T = K*Q^T, O^T = V^T*P^T) so softmax + rescale are lane-local.
// q: [2,32,2048,128], k/v: [2,8,2048,128] (rep=4), out fp32 [2,32,2048,128].

typedef __bf16 bf16_t;
typedef __bf16 bf16x8 __attribute__((ext_vector_type(8)));
typedef float f32x4v __attribute__((ext_vector_type(4)));
typedef float f32x16 __attribute__((ext_vector_type(16)));
typedef unsigned int u32;
typedef u32 u32x4 __attribute__((ext_vector_type(4)));

constexpr int B_ = 2, HQ = 32, HK = 8, SQ = 2048, D = 128;
constexpr int QT = 128;              // q rows per block (32 per wave x 4 waves)
constexpr int KT = 64;               // kv rows per tile
constexpr int KELEM = 64 * 128;      // bf16 elems: K tile
constexpr int VELEM = 128 * 64;      // bf16 elems: V^T tile
constexpr int BUFE = KELEM + VELEM;  // 16384 elems = 32KB per buffer

__device__ __forceinline__ u32 bfb(float f) {  // f32 -> bf16 bits (RNE)
  u32 u = __float_as_uint(f);
  u += 0x7fffu + ((u >> 16) & 1u);
  return u >> 16;
}
__device__ __forceinline__ bf16_t f2bf(float f) {
  unsigned short hs = (unsigned short)bfb(f);
  bf16_t b; __builtin_memcpy(&b, &hs, 2); return b;
}
__device__ __forceinline__ u32 pkbf(float a, float b) {
  return bfb(a) | (bfb(b) << 16);
}
__device__ __forceinline__ float fexp2(float x) {
#if __has_builtin(__builtin_amdgcn_exp2f)
  return __builtin_amdgcn_exp2f(x);
#else
  return exp2f(x);
#endif
}

__global__ __launch_bounds__(256, 2)
void fa2(const float* __restrict__ qg_, const float* __restrict__ kg_,
         const float* __restrict__ vg_, float* __restrict__ og_)
{
  __shared__ __align__(16) char ldsraw[2 * BUFE * 2];  // 64 KiB
  bf16_t* lds = (bf16_t*)ldsraw;

  const int qt = (int)gridDim.x - 1 - (int)blockIdx.x;  // heavy q-tiles first
  const int bh = blockIdx.y;
  const int b = bh >> 5, h = bh & 31, hk = h >> 2;      // GQA rep=4

  const int tid = threadIdx.x;
  const int wv = tid >> 6, lane = tid & 63;
  const int ln = lane & 31, hx = lane >> 5;

  const int q0 = qt * QT;
  const float* qg = qg_ + ((size_t)(b * HQ + h) * SQ + q0) * D;
  const float* kg = kg_ + (size_t)(b * HK + hk) * SQ * D;
  const float* vg = vg_ + (size_t)(b * HK + hk) * SQ * D;
  float*       og = og_ + ((size_t)(b * HQ + h) * SQ + q0) * D;

  // scale * log2(e) folded into Q; softmax done in exp2 domain
  const float qscale = 0.08838834764831845f * 1.4426950408889634f;

  // ---- Q fragments (B-operand of S^T mfma): B[k=d][n=qrow] ----
  // lane holds Q[qrow = q0+32w+ln][d = 16s + 8*hx + j], s = 0..7
  bf16x8 qf[8];
  {
    const float* qrow = qg + (size_t)(32 * wv + ln) * D;
#pragma unroll
    for (int s = 0; s < 8; ++s) {
      const float* p = qrow + 16 * s + 8 * hx;
      f32x4v a = *(const f32x4v*)p;
      f32x4v c = *(const f32x4v*)(p + 4);
      bf16x8 t;
      t[0] = f2bf(a[0] * qscale); t[1] = f2bf(a[1] * qscale);
      t[2] = f2bf(a[2] * qscale); t[3] = f2bf(a[3] * qscale);
      t[4] = f2bf(c[0] * qscale); t[5] = f2bf(c[1] * qscale);
      t[6] = f2bf(c[2] * qscale); t[7] = f2bf(c[3] * qscale);
      qf[s] = t;
    }
  }

  // O^T accumulators: lane owns qrow = q0+32w+ln; d = (r&3)+8*(r>>2)+4*hx+32*mb
  f32x16 Oa[4];
#pragma unroll
  for (int mb = 0; mb < 4; ++mb)
#pragma unroll
    for (int r = 0; r < 16; ++r) Oa[mb][r] = 0.f;
  float m = -1e30f, l = 0.f;

  const int qrow_g = q0 + 32 * wv + ln;  // this lane's global q row
  const int wlast  = q0 + 32 * wv + 31;  // wave's last q row
  const int kv_end = q0 + QT;

  // staging thread assignments
  const int krow = tid >> 2, kq = tid & 3;   // K: row 0..63, 32-col quarter
  const int vkh = tid & 7,  vd4 = tid >> 3;  // V: 8-key group, 4-d group

  f32x4v kst[8], vst[8];

  auto kstage_load = [&](int kb) {
    const float* src = kg + (size_t)(kb + krow) * D + kq * 32;
#pragma unroll
    for (int it = 0; it < 4; ++it) {
      kst[2 * it]     = *(const f32x4v*)(src + 8 * it);
      kst[2 * it + 1] = *(const f32x4v*)(src + 8 * it + 4);
    }
  };
  auto kstage_write = [&](int buf) {
    bf16_t* kbp = lds + buf * BUFE;
#pragma unroll
    for (int it = 0; it < 4; ++it) {
      const int cb = (kq * 4 + it) ^ (krow & 7);  // XOR swizzle (T2)
      bf16x8 w;
      w[0] = f2bf(kst[2*it][0]);   w[1] = f2bf(kst[2*it][1]);
      w[2] = f2bf(kst[2*it][2]);   w[3] = f2bf(kst[2*it][3]);
      w[4] = f2bf(kst[2*it+1][0]); w[5] = f2bf(kst[2*it+1][1]);
      w[6] = f2bf(kst[2*it+1][2]); w[7] = f2bf(kst[2*it+1][3]);
      *(bf16x8*)(kbp + krow * 128 + cb * 8) = w;
    }
  };
  auto vstage_load = [&](int kb) {
    const float* src = vg + (size_t)(kb + 8 * vkh) * D + 4 * vd4;
#pragma unroll
    for (int i = 0; i < 8; ++i) vst[i] = *(const f32x4v*)(src + (size_t)i * D);
  };
  auto vstage_write = [&](int buf) {
    bf16_t* vbp = lds + buf * BUFE + KELEM;
#pragma unroll
    for (int j = 0; j < 4; ++j) {
      const int d = 4 * vd4 + j;
      const int cb = vkh ^ (d & 7);
      bf16x8 w;
#pragma unroll
      for (int i = 0; i < 8; ++i) w[i] = f2bf(vst[i][j]);
      *(bf16x8*)(vbp + d * 64 + cb * 8) = w;
    }
  };

  // prologue: stage tile 0 into buf 0
  kstage_load(0);  kstage_write(0);
  vstage_load(0);  vstage_write(0);
  __syncthreads();

  int cur = 0;
  for (int kb = 0; kb < kv_end; kb += KT) {
    const bool nx  = (kb + KT < kv_end);
    const bool act = (kb <= wlast);  // wave has >=1 unmasked key this tile

    if (nx) kstage_load(kb + KT);  // issue K loads early; hide under QK+softmax

    u32x4 pa[4];  // packed P fragments (B-operand of PV), ks = 0..3
    if (act) {
      // ---- S^T = K * Q^T : D[m=key][n=qrow], lane col = qrow ----
      const bf16_t* kbp = lds + cur * BUFE;
      f32x16 s0, s1;
#pragma unroll
      for (int r = 0; r < 16; ++r) { s0[r] = 0.f; s1[r] = 0.f; }
#pragma unroll
      for (int s = 0; s < 8; ++s) {
        const int cb = (2 * s + hx) ^ (ln & 7);  // (ln+32)&7 == ln&7
        bf16x8 k0 = *(const bf16x8*)(kbp + ln * 128 + cb * 8);
        bf16x8 k1 = *(const bf16x8*)(kbp + (ln + 32) * 128 + cb * 8);
        s0 = __builtin_amdgcn_mfma_f32_32x32x16_bf16(k0, qf[s], s0, 0, 0, 0);
        s1 = __builtin_amdgcn_mfma_f32_32x32x16_bf16(k1, qf[s], s1, 0, 0, 0);
      }

      // causal mask (tail tiles only): key = kb + (r&3)+8*(r>>2)+4*hx (+32)
      if (kb + 63 > q0 + 32 * wv) {
#pragma unroll
        for (int r = 0; r < 16; ++r) {
          const int kl = (r & 3) + 8 * (r >> 2) + 4 * hx;
          if (kb + kl > qrow_g)      s0[r] = -1e30f;
          if (kb + 32 + kl > qrow_g) s1[r] = -1e30f;
        }
      }

      // ---- online softmax, lane-local row (log2 domain) ----
      float tm = -1e30f;
#pragma unroll
      for (int r = 0; r < 16; ++r) tm = fmaxf(tm, fmaxf(s0[r], s1[r]));
      tm = fmaxf(tm, __shfl_xor(tm, 32, 64));  // combine lane halves (same row)

      if (__any(tm > m + 8.f)) {  // defer-max (T13), THR=8 in log2 domain
        const float mn = fmaxf(m, tm);
        const float corr = fexp2(m - mn);
        m = mn; l *= corr;
#pragma unroll
        for (int mb = 0; mb < 4; ++mb)
#pragma unroll
          for (int r = 0; r < 16; ++r) Oa[mb][r] *= corr;
      }

      f32x16 p0, p1;
#pragma unroll
      for (int r = 0; r < 16; ++r) {
        p0[r] = fexp2(s0[r] - m);
        p1[r] = fexp2(s1[r] - m);
      }
      float ps = 0.f;
#pragma unroll
      for (int r = 0; r < 16; ++r) ps += p0[r] + p1[r];
      ps += __shfl_xor(ps, 32, 64);
      l += ps;

      // ---- pack P -> bf16 B-frags with cross-half exchange (T12-style) ----
#pragma unroll
      for (int kb2 = 0; kb2 < 2; ++kb2) {
        const f32x16& pp = kb2 ? p1 : p0;
#pragma unroll
        for (int s2 = 0; s2 < 2; ++s2) {
          const u32 A0 = pkbf(pp[8*s2+0], pp[8*s2+1]);
          const u32 A1 = pkbf(pp[8*s2+2], pp[8*s2+3]);
          const u32 B0 = pkbf(pp[8*s2+4], pp[8*s2+5]);
          const u32 B1 = pkbf(pp[8*s2+6], pp[8*s2+7]);
          const u32 sA0 = __shfl_xor(A0, 32, 64), sA1 = __shfl_xor(A1, 32, 64);
          const u32 sB0 = __shfl_xor(B0, 32, 64), sB1 = __shfl_xor(B1, 32, 64);
          const int ks = 2 * kb2 + s2;
          pa[ks][0] = hx ? sB0 : A0;
          pa[ks][1] = hx ? sB1 : A1;
          pa[ks][2] = hx ? B0 : sA0;
          pa[ks][3] = hx ? B1 : sA1;
        }
      }
    }

    if (nx) kstage_write(cur ^ 1);   // vmcnt waits auto-inserted at first use
    if (nx) vstage_load(kb + KT);    // issue V loads; hide under PV

    if (act) {
      // ---- O^T += V^T * P^T : D[m=d][n=qrow] ----
      const bf16_t* vbp = lds + cur * BUFE + KELEM;
#pragma unroll
      for (int mb = 0; mb < 4; ++mb) {
        const int d0 = ln + 32 * mb;
#pragma unroll
        for (int ks = 0; ks < 4; ++ks) {
          const int cb = (hx + 2 * ks) ^ (d0 & 7);
          bf16x8 vf = *(const bf16x8*)(vbp + d0 * 64 + cb * 8);
          Oa[mb] = __builtin_amdgcn_mfma_f32_32x32x16_bf16(
              vf, __builtin_bit_cast(bf16x8, pa[ks]), Oa[mb], 0, 0, 0);
        }
      }
    }

    if (nx) vstage_write(cur ^ 1);
    __syncthreads();
    cur ^= 1;
  }

  // ---- epilogue: normalize, transpose via LDS (swizzled), coalesced store ----
  float* ol = (float*)ldsraw;           // reuse 64KB as 4 x [32][128] f32
  float* wbase = ol + wv * 4096;
  const float inv = 1.f / l;
#pragma unroll
  for (int mb = 0; mb < 4; ++mb) {
#pragma unroll
    for (int g = 0; g < 4; ++g) {
      f32x4v v4;
      v4[0] = Oa[mb][4*g+0] * inv; v4[1] = Oa[mb][4*g+1] * inv;
      v4[2] = Oa[mb][4*g+2] * inv; v4[3] = Oa[mb][4*g+3] * inv;
      const int chunk = (2 * g + hx + 8 * mb) ^ (ln & 7);  // swizzled f32x4 slot
      *(f32x4v*)(wbase + ln * 128 + chunk * 4) = v4;
    }
  }
  __syncthreads();
#pragma unroll
  for (int i = 0; i < 16; ++i) {
    const int q2 = 2 * i + hx;            // 2 rows per instr -> 1KB contiguous
    const int cs = ln ^ (q2 & 7);
    f32x4v v4 = *(const f32x4v*)(wbase + q2 * 128 + cs * 4);
    *(f32x4v*)(og + (size_t)(32 * wv + q2) * D + 4 * ln) = v4;
  }
}

extern "C" void kernel_launch(void* const* d_in, const int* in_sizes, int n_in,
                              void* d_out, int out_size, void* d_ws, size_t ws_size,
                              hipStream_t stream) {
  const float* q = (const float*)d_in[0];
  const float* k = (const float*)d_in[1];
  const float* v = (const float*)d_in[2];
  float* out = (float*)d_out;
  dim3 grid(SQ / QT, B_ * HQ);  // 16 q-tiles x 64 batch-heads
  fa2<<<grid, 256, 0, stream>>>(q, k, v, out);
}

// Round 3
// 218.263 us; speedup vs baseline: 2.6353x; 1.1356x over previous
//
#include <hip/hip_runtime.h>

// Causal GQA flash-attention fwd, fp32 I/O, bf16 32x32x16 MFMA.
// Structure: prepass converts K/V fp32 -> bf16 swizzled LDS tile images in
// d_ws (once), main kernel stages tiles with global_load_lds DMA (no VALU,
// no staging regs), swapped-operand S^T = K*Q^T and O^T = V^T*P^T so softmax
// and rescale are lane-local. q:[2,32,2048,128] k/v:[2,8,2048,128] rep=4.

typedef __bf16 bf16_t;
typedef __bf16 bf16x2 __attribute__((ext_vector_type(2)));
typedef __bf16 bf16x8 __attribute__((ext_vector_type(8)));
typedef float f32x4v __attribute__((ext_vector_type(4)));
typedef float f32x16 __attribute__((ext_vector_type(16)));
typedef unsigned int u32;
typedef u32 u32x4 __attribute__((ext_vector_type(4)));

constexpr int B_ = 2, HQ = 32, HK = 8, SQ = 2048, D = 128;
constexpr int QT = 256, KT = 64;
constexpr int NT = SQ / KT;                   // 32 kv tiles per (b,hk)
constexpr int TILE_ELEM = KT * D * 2;         // 16384 bf16 = K(8192) + V(8192)
constexpr size_t TILE_BYTES = TILE_ELEM * 2;  // 32 KiB
constexpr size_t WS_NEED = (size_t)B_ * HK * NT * TILE_BYTES;  // 16 MiB

__device__ __forceinline__ u32 pkbf(float a, float b) {  // packed f32x2->bf16x2
  bf16x2 t; t[0] = (bf16_t)a; t[1] = (bf16_t)b;
  return __builtin_bit_cast(u32, t);
}
__device__ __forceinline__ float fexp2(float x) { return __builtin_exp2f(x); }

__device__ __forceinline__ void gl_lds16(const void* g, void* l) {
  __builtin_amdgcn_global_load_lds(
      (const __attribute__((address_space(1))) u32*)g,
      (__attribute__((address_space(3))) u32*)l, 16, 0, 0);
}

// ---------------- prepass: build bf16 swizzled tile images in ws -----------
// image per (b,hk,t): K part: row r(64) x 16 slots(16B); phys slot p holds
// K[t*64+r][8*(p^(r&15)) .. +8). V part: row d(128) x 8 slots; phys slot p
// holds V[t*64 + 8*(p^(d&7)) + j][d], j=0..7.
__global__ __launch_bounds__(256)
void prepass(const float* __restrict__ kg, const float* __restrict__ vg,
             bf16_t* __restrict__ ws) {
  const int blk = blockIdx.x;            // (b*HK+hk)*NT + t
  const int bh = blk / NT, t = blk % NT;
  const float* ksrc = kg + ((size_t)bh * SQ + (size_t)t * KT) * D;
  const float* vsrc = vg + ((size_t)bh * SQ + (size_t)t * KT) * D;
  bf16_t* kdst = ws + (size_t)blk * TILE_ELEM;
  bf16_t* vdst = kdst + KT * D;
  const int tid = threadIdx.x;
#pragma unroll
  for (int i = 0; i < 4; ++i) {          // K: 1024 16B chunks
    const int c = tid + 256 * i;
    const int r = c >> 4, p = c & 15, q = p ^ (r & 15);
    const float* s = ksrc + (size_t)r * D + 8 * q;
    f32x4v a = *(const f32x4v*)s;
    f32x4v b = *(const f32x4v*)(s + 4);
    bf16x8 w;
    w[0]=(bf16_t)a[0]; w[1]=(bf16_t)a[1]; w[2]=(bf16_t)a[2]; w[3]=(bf16_t)a[3];
    w[4]=(bf16_t)b[0]; w[5]=(bf16_t)b[1]; w[6]=(bf16_t)b[2]; w[7]=(bf16_t)b[3];
    *(bf16x8*)(kdst + (size_t)r * D + 8 * p) = w;
  }
#pragma unroll
  for (int i = 0; i < 4; ++i) {          // V^T: 1024 16B chunks (L1 absorbs)
    const int c = tid + 256 * i;
    const int d = c >> 3, p = c & 7, q = p ^ (d & 7);
    bf16x8 w;
#pragma unroll
    for (int j = 0; j < 8; ++j) w[j] = (bf16_t)vsrc[(size_t)(8 * q + j) * D + d];
    *(bf16x8*)(vdst + (size_t)d * KT + 8 * p) = w;
  }
}

// ---------------- main kernel ----------------------------------------------
__global__ __launch_bounds__(512, 4)
void fa3(const float* __restrict__ qg_, const bf16_t* __restrict__ ws,
         float* __restrict__ og_) {
  __shared__ __align__(16) char ldsraw[2 * TILE_BYTES];  // 64 KiB dbuf

  const int idx = blockIdx.x;            // 512 blocks
  const int i7 = idx >> 6, bh = idx & 63;
  const int qt = (i7 < 4) ? (7 - i7) : (i7 - 4);  // heavy first + pair-balance
  const int b = bh >> 5, h = bh & 31, hk = h >> 2;

  const int tid = threadIdx.x;
  const int wv = tid >> 6, lane = tid & 63;
  const int ln = lane & 31, hx = lane >> 5;

  const int q0 = qt * QT;
  const float* qg = qg_ + ((size_t)(b * HQ + h) * SQ + q0) * D;
  float*       og = og_ + ((size_t)(b * HQ + h) * SQ + q0) * D;
  const bf16_t* wsrc = ws + (size_t)(b * HK + hk) * NT * TILE_ELEM;

  const float qscale = 0.08838834764831845f * 1.4426950408889634f;  // /sqrt(D)*log2e

  // Q frags: lane holds Q[qrow=q0+32wv+ln][d=16s+8hx+j]
  bf16x8 qf[8];
  {
    const float* qrp = qg + (size_t)(32 * wv + ln) * D + 8 * hx;
#pragma unroll
    for (int s = 0; s < 8; ++s) {
      f32x4v a = *(const f32x4v*)(qrp + 16 * s);
      f32x4v c = *(const f32x4v*)(qrp + 16 * s + 4);
      bf16x8 t;
      t[0]=(bf16_t)(a[0]*qscale); t[1]=(bf16_t)(a[1]*qscale);
      t[2]=(bf16_t)(a[2]*qscale); t[3]=(bf16_t)(a[3]*qscale);
      t[4]=(bf16_t)(c[0]*qscale); t[5]=(bf16_t)(c[1]*qscale);
      t[6]=(bf16_t)(c[2]*qscale); t[7]=(bf16_t)(c[3]*qscale);
      qf[s] = t;
    }
  }

  f32x16 Oa[4];
#pragma unroll
  for (int mb = 0; mb < 4; ++mb)
#pragma unroll
    for (int r = 0; r < 16; ++r) Oa[mb][r] = 0.f;
  float m = -1e30f, l = 0.f;

  const int wrow = q0 + 32 * wv;         // wave's first q row
  const int qrow_g = wrow + ln;
  const int ntile = (q0 + QT) / KT;

  // DMA staging: 32 KiB image = 32 chunks of 1 KiB; wave wv owns chunks wv+8i
  auto stage = [&](int t, int buf) {
    const char* src = (const char*)(wsrc + (size_t)t * TILE_ELEM);
    char* dst = ldsraw + (size_t)buf * TILE_BYTES;
#pragma unroll
    for (int i = 0; i < 4; ++i) {
      const int chunk = wv + 8 * i;
      gl_lds16(src + chunk * 1024 + lane * 16, dst + chunk * 1024);
    }
  };

  stage(0, 0);
  __syncthreads();

  int cur = 0;
  for (int ti = 0; ti < ntile; ++ti) {
    const int kb = ti * KT;
    if (ti + 1 < ntile) stage(ti + 1, cur ^ 1);

    const bf16_t* kbp = (const bf16_t*)(ldsraw + (size_t)cur * TILE_BYTES);
    const bf16_t* vbp = kbp + KT * D;

    for (int half = 0; half < 2; ++half) {
      const int kb2 = kb + 32 * half;
      if (kb2 > wrow + 31) break;        // wave-uniform causal skip

      // ---- S^T = K * Q^T (32 keys) ----
      const int rbase = ln + 32 * half;
      f32x16 sa;
#pragma unroll
      for (int r = 0; r < 16; ++r) sa[r] = 0.f;
#pragma unroll
      for (int s = 0; s < 8; ++s) {
        const int cb = (2 * s + hx) ^ (rbase & 15);
        bf16x8 kf = *(const bf16x8*)(kbp + rbase * 128 + cb * 8);
        sa = __builtin_amdgcn_mfma_f32_32x32x16_bf16(kf, qf[s], sa, 0, 0, 0);
      }

      // causal mask (diagonal sub-tiles only)
      if (kb2 + 31 > wrow) {
#pragma unroll
        for (int r = 0; r < 16; ++r) {
          const int kl = (r & 3) + 8 * (r >> 2) + 4 * hx;
          if (kb2 + kl > qrow_g) sa[r] = -1e30f;
        }
      }

      // ---- online softmax (lane-local row, log2 domain) ----
      float tm = -1e30f;
#pragma unroll
      for (int r = 0; r < 16; ++r) tm = fmaxf(tm, sa[r]);
      tm = fmaxf(tm, __shfl_xor(tm, 32, 64));
      if (__any(tm > m + 8.f)) {         // defer-max (T13)
        const float mn = fmaxf(m, tm);
        const float corr = fexp2(m - mn);
        m = mn; l *= corr;
#pragma unroll
        for (int mb = 0; mb < 4; ++mb)
#pragma unroll
          for (int r = 0; r < 16; ++r) Oa[mb][r] *= corr;
      }
#pragma unroll
      for (int r = 0; r < 16; ++r) sa[r] = fexp2(sa[r] - m);
      float ps = 0.f;
#pragma unroll
      for (int r = 0; r < 16; ++r) ps += sa[r];
      ps += __shfl_xor(ps, 32, 64);
      l += ps;

      // ---- pack P -> bf16 B-frags with cross-half exchange ----
      u32x4 pa[2];
#pragma unroll
      for (int s2 = 0; s2 < 2; ++s2) {
        const u32 A0 = pkbf(sa[8*s2+0], sa[8*s2+1]);
        const u32 A1 = pkbf(sa[8*s2+2], sa[8*s2+3]);
        const u32 B0 = pkbf(sa[8*s2+4], sa[8*s2+5]);
        const u32 B1 = pkbf(sa[8*s2+6], sa[8*s2+7]);
        const u32 sA0 = __shfl_xor(A0, 32, 64), sA1 = __shfl_xor(A1, 32, 64);
        const u32 sB0 = __shfl_xor(B0, 32, 64), sB1 = __shfl_xor(B1, 32, 64);
        pa[s2][0] = hx ? sB0 : A0;
        pa[s2][1] = hx ? sB1 : A1;
        pa[s2][2] = hx ? B0 : sA0;
        pa[s2][3] = hx ? B1 : sA1;
      }

      // ---- O^T += V^T * P^T for this 32-key half ----
#pragma unroll
      for (int s2 = 0; s2 < 2; ++s2) {
#pragma unroll
        for (int mb = 0; mb < 4; ++mb) {
          const int d0 = ln + 32 * mb;
          const int cb = (4 * half + 2 * s2 + hx) ^ (d0 & 7);
          bf16x8 vf = *(const bf16x8*)(vbp + d0 * 64 + cb * 8);
          Oa[mb] = __builtin_amdgcn_mfma_f32_32x32x16_bf16(
              vf, __builtin_bit_cast(bf16x8, pa[s2]), Oa[mb], 0, 0, 0);
        }
      }
    }

    __syncthreads();
    cur ^= 1;
  }

  // ---- epilogue: per-wave LDS transpose (8 KiB each), coalesced stores ----
  const float inv = 1.f / l;
  float* wlds = (float*)ldsraw + wv * 2048;
#pragma unroll
  for (int h2 = 0; h2 < 2; ++h2) {
#pragma unroll
    for (int mb2 = 0; mb2 < 2; ++mb2) {
      const int mb = 2 * h2 + mb2;
#pragma unroll
      for (int g = 0; g < 4; ++g) {
        f32x4v v4;
        v4[0] = Oa[mb][4*g+0] * inv; v4[1] = Oa[mb][4*g+1] * inv;
        v4[2] = Oa[mb][4*g+2] * inv; v4[3] = Oa[mb][4*g+3] * inv;
        const int lslot = 2 * g + hx + 8 * mb2;
        const int pslot = lslot ^ (ln & 15);
        *(f32x4v*)(wlds + ln * 64 + pslot * 4) = v4;
      }
    }
    asm volatile("s_waitcnt lgkmcnt(0)" ::: "memory");
    __builtin_amdgcn_sched_barrier(0);
#pragma unroll
    for (int i = 0; i < 8; ++i) {
      const int q2 = 4 * i + (lane >> 4);
      const int lsl = lane & 15;
      const int psl = lsl ^ (q2 & 15);
      f32x4v v4 = *(const f32x4v*)(wlds + q2 * 64 + psl * 4);
      *(f32x4v*)(og + (size_t)(32 * wv + q2) * D + 64 * h2 + 4 * lsl) = v4;
    }
    __builtin_amdgcn_sched_barrier(0);
  }
}

// ---------------- fallback (round-2 kernel, used if ws too small) ----------
namespace fb {
typedef float f32x4 __attribute__((ext_vector_type(4)));
constexpr int QT2 = 128, KT2 = 64;
constexpr int KELEM = 64 * 128, VELEM = 128 * 64, BUFE = KELEM + VELEM;

__device__ __forceinline__ u32 bfb(float f) {
  u32 u = __float_as_uint(f);
  u += 0x7fffu + ((u >> 16) & 1u);
  return u >> 16;
}
__device__ __forceinline__ bf16_t f2bf(float f) {
  unsigned short hs = (unsigned short)bfb(f);
  bf16_t b; __builtin_memcpy(&b, &hs, 2); return b;
}

__global__ __launch_bounds__(256, 2)
void fa2(const float* __restrict__ qg_, const float* __restrict__ kg_,
         const float* __restrict__ vg_, float* __restrict__ og_)
{
  __shared__ __align__(16) char ldsraw[2 * BUFE * 2];
  bf16_t* lds = (bf16_t*)ldsraw;
  const int qt = (int)gridDim.x - 1 - (int)blockIdx.x;
  const int bh = blockIdx.y;
  const int b = bh >> 5, h = bh & 31, hk = h >> 2;
  const int tid = threadIdx.x;
  const int wv = tid >> 6, lane = tid & 63;
  const int ln = lane & 31, hx = lane >> 5;
  const int q0 = qt * QT2;
  const float* qg = qg_ + ((size_t)(b * HQ + h) * SQ + q0) * D;
  const float* kg = kg_ + (size_t)(b * HK + hk) * SQ * D;
  const float* vg = vg_ + (size_t)(b * HK + hk) * SQ * D;
  float*       og = og_ + ((size_t)(b * HQ + h) * SQ + q0) * D;
  const float qscale = 0.08838834764831845f * 1.4426950408889634f;
  bf16x8 qf[8];
  {
    const float* qrow = qg + (size_t)(32 * wv + ln) * D;
#pragma unroll
    for (int s = 0; s < 8; ++s) {
      const float* p = qrow + 16 * s + 8 * hx;
      f32x4 a = *(const f32x4*)p;
      f32x4 c = *(const f32x4*)(p + 4);
      bf16x8 t;
      t[0]=f2bf(a[0]*qscale); t[1]=f2bf(a[1]*qscale);
      t[2]=f2bf(a[2]*qscale); t[3]=f2bf(a[3]*qscale);
      t[4]=f2bf(c[0]*qscale); t[5]=f2bf(c[1]*qscale);
      t[6]=f2bf(c[2]*qscale); t[7]=f2bf(c[3]*qscale);
      qf[s] = t;
    }
  }
  f32x16 Oa[4];
#pragma unroll
  for (int mb = 0; mb < 4; ++mb)
#pragma unroll
    for (int r = 0; r < 16; ++r) Oa[mb][r] = 0.f;
  float m = -1e30f, l = 0.f;
  const int qrow_g = q0 + 32 * wv + ln;
  const int wlast = q0 + 32 * wv + 31;
  const int kv_end = q0 + QT2;
  const int krow = tid >> 2, kq = tid & 3;
  const int vkh = tid & 7, vd4 = tid >> 3;
  f32x4 kst[8], vst[8];
  auto kstage_load = [&](int kb) {
    const float* src = kg + (size_t)(kb + krow) * D + kq * 32;
#pragma unroll
    for (int it = 0; it < 4; ++it) {
      kst[2*it]   = *(const f32x4*)(src + 8 * it);
      kst[2*it+1] = *(const f32x4*)(src + 8 * it + 4);
    }
  };
  auto kstage_write = [&](int buf) {
    bf16_t* kbp = lds + buf * BUFE;
#pragma unroll
    for (int it = 0; it < 4; ++it) {
      const int cb = (kq * 4 + it) ^ (krow & 7);
      bf16x8 w;
      w[0]=f2bf(kst[2*it][0]);   w[1]=f2bf(kst[2*it][1]);
      w[2]=f2bf(kst[2*it][2]);   w[3]=f2bf(kst[2*it][3]);
      w[4]=f2bf(kst[2*it+1][0]); w[5]=f2bf(kst[2*it+1][1]);
      w[6]=f2bf(kst[2*it+1][2]); w[7]=f2bf(kst[2*it+1][3]);
      *(bf16x8*)(kbp + krow * 128 + cb * 8) = w;
    }
  };
  auto vstage_load = [&](int kb) {
    const float* src = vg + (size_t)(kb + 8 * vkh) * D + 4 * vd4;
#pragma unroll
    for (int i = 0; i < 8; ++i) vst[i] = *(const f32x4*)(src + (size_t)i * D);
  };
  auto vstage_write = [&](int buf) {
    bf16_t* vbp = lds + buf * BUFE + KELEM;
#pragma unroll
    for (int j = 0; j < 4; ++j) {
      const int d = 4 * vd4 + j;
      const int cb = vkh ^ (d & 7);
      bf16x8 w;
#pragma unroll
      for (int i = 0; i < 8; ++i) w[i] = f2bf(vst[i][j]);
      *(bf16x8*)(vbp + d * 64 + cb * 8) = w;
    }
  };
  kstage_load(0); kstage_write(0);
  vstage_load(0); vstage_write(0);
  __syncthreads();
  int cur = 0;
  for (int kb = 0; kb < kv_end; kb += KT2) {
    const bool nx = (kb + KT2 < kv_end);
    const bool act = (kb <= wlast);
    if (nx) kstage_load(kb + KT2);
    u32x4 pa[4];
    if (act) {
      const bf16_t* kbp = lds + cur * BUFE;
      f32x16 s0, s1;
#pragma unroll
      for (int r = 0; r < 16; ++r) { s0[r] = 0.f; s1[r] = 0.f; }
#pragma unroll
      for (int s = 0; s < 8; ++s) {
        const int cb = (2 * s + hx) ^ (ln & 7);
        bf16x8 k0 = *(const bf16x8*)(kbp + ln * 128 + cb * 8);
        bf16x8 k1 = *(const bf16x8*)(kbp + (ln + 32) * 128 + cb * 8);
        s0 = __builtin_amdgcn_mfma_f32_32x32x16_bf16(k0, qf[s], s0, 0, 0, 0);
        s1 = __builtin_amdgcn_mfma_f32_32x32x16_bf16(k1, qf[s], s1, 0, 0, 0);
      }
      if (kb + 63 > q0 + 32 * wv) {
#pragma unroll
        for (int r = 0; r < 16; ++r) {
          const int kl = (r & 3) + 8 * (r >> 2) + 4 * hx;
          if (kb + kl > qrow_g)      s0[r] = -1e30f;
          if (kb + 32 + kl > qrow_g) s1[r] = -1e30f;
        }
      }
      float tm = -1e30f;
#pragma unroll
      for (int r = 0; r < 16; ++r) tm = fmaxf(tm, fmaxf(s0[r], s1[r]));
      tm = fmaxf(tm, __shfl_xor(tm, 32, 64));
      if (__any(tm > m + 8.f)) {
        const float mn = fmaxf(m, tm);
        const float corr = fexp2(m - mn);
        m = mn; l *= corr;
#pragma unroll
        for (int mb = 0; mb < 4; ++mb)
#pragma unroll
          for (int r = 0; r < 16; ++r) Oa[mb][r] *= corr;
      }
      f32x16 p0, p1;
#pragma unroll
      for (int r = 0; r < 16; ++r) {
        p0[r] = fexp2(s0[r] - m);
        p1[r] = fexp2(s1[r] - m);
      }
      float ps = 0.f;
#pragma unroll
      for (int r = 0; r < 16; ++r) ps += p0[r] + p1[r];
      ps += __shfl_xor(ps, 32, 64);
      l += ps;
#pragma unroll
      for (int kb2 = 0; kb2 < 2; ++kb2) {
        const f32x16& pp = kb2 ? p1 : p0;
#pragma unroll
        for (int s2 = 0; s2 < 2; ++s2) {
          const u32 A0 = pkbf(pp[8*s2+0], pp[8*s2+1]);
          const u32 A1 = pkbf(pp[8*s2+2], pp[8*s2+3]);
          const u32 B0 = pkbf(pp[8*s2+4], pp[8*s2+5]);
          const u32 B1 = pkbf(pp[8*s2+6], pp[8*s2+7]);
          const u32 sA0 = __shfl_xor(A0, 32, 64), sA1 = __shfl_xor(A1, 32, 64);
          const u32 sB0 = __shfl_xor(B0, 32, 64), sB1 = __shfl_xor(B1, 32, 64);
          const int ks = 2 * kb2 + s2;
          pa[ks][0] = hx ? sB0 : A0;
          pa[ks][1] = hx ? sB1 : A1;
          pa[ks][2] = hx ? B0 : sA0;
          pa[ks][3] = hx ? B1 : sA1;
        }
      }
    }
    if (nx) kstage_write(cur ^ 1);
    if (nx) vstage_load(kb + KT2);
    if (act) {
      const bf16_t* vbp = lds + cur * BUFE + KELEM;
#pragma unroll
      for (int mb = 0; mb < 4; ++mb) {
        const int d0 = ln + 32 * mb;
#pragma unroll
        for (int ks = 0; ks < 4; ++ks) {
          const int cb = (hx + 2 * ks) ^ (d0 & 7);
          bf16x8 vf = *(const bf16x8*)(vbp + d0 * 64 + cb * 8);
          Oa[mb] = __builtin_amdgcn_mfma_f32_32x32x16_bf16(
              vf, __builtin_bit_cast(bf16x8, pa[ks]), Oa[mb], 0, 0, 0);
        }
      }
    }
    if (nx) vstage_write(cur ^ 1);
    __syncthreads();
    cur ^= 1;
  }
  float* ol = (float*)ldsraw;
  float* wbase = ol + wv * 4096;
  const float inv = 1.f / l;
#pragma unroll
  for (int mb = 0; mb < 4; ++mb) {
#pragma unroll
    for (int g = 0; g < 4; ++g) {
      f32x4 v4;
      v4[0] = Oa[mb][4*g+0]*inv; v4[1] = Oa[mb][4*g+1]*inv;
      v4[2] = Oa[mb][4*g+2]*inv; v4[3] = Oa[mb][4*g+3]*inv;
      const int chunk = (2 * g + hx + 8 * mb) ^ (ln & 7);
      *(f32x4*)(wbase + ln * 128 + chunk * 4) = v4;
    }
  }
  __syncthreads();
#pragma unroll
  for (int i = 0; i < 16; ++i) {
    const int q2 = 2 * i + hx;
    const int cs = ln ^ (q2 & 7);
    f32x4 v4 = *(const f32x4*)(wbase + q2 * 128 + cs * 4);
    *(f32x4*)(og + (size_t)(32 * wv + q2) * D + 4 * ln) = v4;
  }
}
}  // namespace fb

extern "C" void kernel_launch(void* const* d_in, const int* in_sizes, int n_in,
                              void* d_out, int out_size, void* d_ws, size_t ws_size,
                              hipStream_t stream) {
  const float* q = (const float*)d_in[0];
  const float* k = (const float*)d_in[1];
  const float* v = (const float*)d_in[2];
  float* out = (float*)d_out;
  if (ws_size >= WS_NEED) {
    prepass<<<dim3(B_ * HK * NT), 256, 0, stream>>>(k, v, (bf16_t*)d_ws);
    fa3<<<dim3((SQ / QT) * B_ * HQ), 512, 0, stream>>>(q, (const bf16_t*)d_ws, out);
  } else {
    fb::fa2<<<dim3(SQ / fb::QT2, B_ * HQ), 256, 0, stream>>>(q, k, v, out);
  }
}

// Round 4
// 166.216 us; speedup vs baseline: 3.4605x; 1.3131x over previous
//
#include <hip/hip_runtime.h>

// Causal GQA flash-attention fwd, fp32 I/O, bf16 32x32x16 MFMA.
// Prepass converts K/V fp32 -> bf16 swizzled 32-key tile images in d_ws once;
// main kernel: 4-wave blocks (QT=128, 32 rows/wave), KT=32 double-buffered
// 32KiB LDS -> 4 blocks/CU, global_load_lds staging, swapped-operand
// S^T = K*Q^T and O^T = V^T*P^T (lane-local softmax), LPT heavy-first grid.

typedef __bf16 bf16_t;
typedef __bf16 bf16x2 __attribute__((ext_vector_type(2)));
typedef __bf16 bf16x8 __attribute__((ext_vector_type(8)));
typedef float f32x4v __attribute__((ext_vector_type(4)));
typedef float f32x16 __attribute__((ext_vector_type(16)));
typedef unsigned int u32;
typedef u32 u32x4 __attribute__((ext_vector_type(4)));

constexpr int B_ = 2, HQ = 32, HK = 8, SQ = 2048, D = 128;
constexpr int QT = 128, KT = 32;
constexpr int NQT = SQ / QT;                  // 16 q-tiles
constexpr int NT = SQ / KT;                   // 64 kv tiles per (b,hk)
constexpr int TILE_ELEM = KT * D * 2;         // 8192 bf16 = K(4096) + V(4096)
constexpr size_t TILE_BYTES = TILE_ELEM * 2;  // 16 KiB
constexpr size_t WS_NEED = (size_t)B_ * HK * NT * TILE_BYTES;  // 16 MiB

__device__ __forceinline__ u32 pkbf(float a, float b) {  // f32x2 -> bf16x2
  bf16x2 t; t[0] = (bf16_t)a; t[1] = (bf16_t)b;
  return __builtin_bit_cast(u32, t);
}
__device__ __forceinline__ float fexp2(float x) { return __builtin_exp2f(x); }

__device__ __forceinline__ void gl_lds16(const void* g, void* l) {
  __builtin_amdgcn_global_load_lds(
      (const __attribute__((address_space(1))) u32*)g,
      (__attribute__((address_space(3))) u32*)l, 16, 0, 0);
}

// ---------------- prepass: bf16 swizzled 32-key tile images ----------------
// Per (b,hk,t) 16 KiB image:
//  K part: row r(32) x 16 slots of 16B; phys slot p holds K[t*32+r][8*(p^(r&15))..+8)
//  V part: row d(128) x 4 slots of 16B; phys slot p holds V[t*32+8*(p^(d&3))+j][d]
__global__ __launch_bounds__(256)
void prepass(const float* __restrict__ kg, const float* __restrict__ vg,
             bf16_t* __restrict__ ws) {
  const int blk = blockIdx.x;            // bh*NT + t
  const int bh = blk >> 6, t = blk & 63;
  const float* ksrc = kg + ((size_t)bh * SQ + (size_t)t * KT) * D;
  const float* vsrc = vg + ((size_t)bh * SQ + (size_t)t * KT) * D;
  bf16_t* kdst = ws + (size_t)blk * TILE_ELEM;
  bf16_t* vdst = kdst + KT * D;
  const int tid = threadIdx.x;
#pragma unroll
  for (int i = 0; i < 2; ++i) {          // K: 512 16B chunks
    const int c = tid + 256 * i;
    const int r = c >> 4, p = c & 15, q = p ^ (r & 15);
    const float* s = ksrc + (size_t)r * D + 8 * q;
    f32x4v a = *(const f32x4v*)s;
    f32x4v b = *(const f32x4v*)(s + 4);
    bf16x8 w;
    w[0]=(bf16_t)a[0]; w[1]=(bf16_t)a[1]; w[2]=(bf16_t)a[2]; w[3]=(bf16_t)a[3];
    w[4]=(bf16_t)b[0]; w[5]=(bf16_t)b[1]; w[6]=(bf16_t)b[2]; w[7]=(bf16_t)b[3];
    *(bf16x8*)(kdst + (size_t)r * D + 8 * p) = w;
  }
#pragma unroll
  for (int i = 0; i < 2; ++i) {          // V^T: 512 16B chunks
    const int c = tid + 256 * i;
    const int d = c >> 2, p = c & 3, q = p ^ (d & 3);
    bf16x8 w;
#pragma unroll
    for (int j = 0; j < 8; ++j) w[j] = (bf16_t)vsrc[(size_t)(8 * q + j) * D + d];
    *(bf16x8*)(vdst + (size_t)d * KT + 8 * p) = w;
  }
}

// ---------------- main kernel ----------------------------------------------
__global__ __launch_bounds__(256, 4)
void fa4(const float* __restrict__ qg_, const bf16_t* __restrict__ ws,
         float* __restrict__ og_) {
  __shared__ __align__(16) char ldsraw[2 * TILE_BYTES];  // 32 KiB dbuf

  const int idx = blockIdx.x;            // 1024 blocks, heaviest first
  const int g = idx >> 6, bh = idx & 63;
  const int qt = (NQT - 1) - g;          // qt = 15..0
  const int b = bh >> 5, h = bh & 31, hk = h >> 2;

  const int tid = threadIdx.x;
  const int wv = tid >> 6, lane = tid & 63;
  const int ln = lane & 31, hx = lane >> 5;

  const int q0 = qt * QT;
  const float* qg = qg_ + ((size_t)(b * HQ + h) * SQ + q0) * D;
  float*       og = og_ + ((size_t)(b * HQ + h) * SQ + q0) * D;
  const bf16_t* wsrc = ws + (size_t)(b * HK + hk) * NT * TILE_ELEM;

  // DMA staging: 16 KiB image = 16 chunks of 1 KiB; wave wv owns chunks 4wv+i
  auto stage = [&](int t, int buf) {
    const char* src = (const char*)(wsrc + (size_t)t * TILE_ELEM);
    char* dst = ldsraw + (size_t)buf * TILE_BYTES;
#pragma unroll
    for (int i = 0; i < 4; ++i) {
      const int chunk = 4 * wv + i;
      gl_lds16(src + chunk * 1024 + lane * 16, dst + chunk * 1024);
    }
  };

  stage(0, 0);  // issue before Q-frag loads so DMA hides under them

  const float qscale = 0.08838834764831845f * 1.4426950408889634f;  // /sqrt(D)*log2e

  // Q frags: lane holds Q[qrow=q0+32wv+ln][d=16s+8hx+j]
  bf16x8 qf[8];
  {
    const float* qrp = qg + (size_t)(32 * wv + ln) * D + 8 * hx;
#pragma unroll
    for (int s = 0; s < 8; ++s) {
      f32x4v a = *(const f32x4v*)(qrp + 16 * s);
      f32x4v c = *(const f32x4v*)(qrp + 16 * s + 4);
      bf16x8 t;
      t[0]=(bf16_t)(a[0]*qscale); t[1]=(bf16_t)(a[1]*qscale);
      t[2]=(bf16_t)(a[2]*qscale); t[3]=(bf16_t)(a[3]*qscale);
      t[4]=(bf16_t)(c[0]*qscale); t[5]=(bf16_t)(c[1]*qscale);
      t[6]=(bf16_t)(c[2]*qscale); t[7]=(bf16_t)(c[3]*qscale);
      qf[s] = t;
    }
  }

  f32x16 Oa[4];
#pragma unroll
  for (int mb = 0; mb < 4; ++mb)
#pragma unroll
    for (int r = 0; r < 16; ++r) Oa[mb][r] = 0.f;
  float m = -1e30f, l = 0.f;

  const int wrow = q0 + 32 * wv;         // wave's first q row (32-aligned)
  const int ntile = q0 / KT + 4;         // tiles this block needs

  __syncthreads();

  int cur = 0;
  for (int ti = 0; ti < ntile; ++ti) {
    const int kb = ti * KT;
    if (ti + 1 < ntile) stage(ti + 1, cur ^ 1);

    if (kb <= wrow) {                    // wave-uniform causal activity
      const bf16_t* kbp = (const bf16_t*)(ldsraw + (size_t)cur * TILE_BYTES);
      const bf16_t* vbp = kbp + KT * D;

      // ---- S^T = K * Q^T (32 keys x 32 qrows per wave) ----
      f32x16 sa;
#pragma unroll
      for (int r = 0; r < 16; ++r) sa[r] = 0.f;
      __builtin_amdgcn_s_setprio(1);
#pragma unroll
      for (int s = 0; s < 8; ++s) {
        const int cb = (2 * s + hx) ^ (ln & 15);
        bf16x8 kf = *(const bf16x8*)(kbp + ln * 128 + cb * 8);
        sa = __builtin_amdgcn_mfma_f32_32x32x16_bf16(kf, qf[s], sa, 0, 0, 0);
      }
      __builtin_amdgcn_s_setprio(0);

      // causal mask: only the diagonal tile (kb == wrow)
      if (kb == wrow) {
#pragma unroll
        for (int r = 0; r < 16; ++r) {
          const int kl = (r & 3) + 8 * (r >> 2) + 4 * hx;
          if (kl > ln) sa[r] = -1e30f;
        }
      }

      // ---- online softmax (lane-local row, log2 domain) ----
      float tm = -1e30f;
#pragma unroll
      for (int r = 0; r < 16; ++r) tm = fmaxf(tm, sa[r]);
      tm = fmaxf(tm, __shfl_xor(tm, 32, 64));
      if (__any(tm > m + 8.f)) {         // defer-max (T13)
        const float mn = fmaxf(m, tm);
        const float corr = fexp2(m - mn);
        m = mn; l *= corr;
#pragma unroll
        for (int mb = 0; mb < 4; ++mb)
#pragma unroll
          for (int r = 0; r < 16; ++r) Oa[mb][r] *= corr;
      }
#pragma unroll
      for (int r = 0; r < 16; ++r) sa[r] = fexp2(sa[r] - m);
      float ps = 0.f;
#pragma unroll
      for (int r = 0; r < 16; ++r) ps += sa[r];
      ps += __shfl_xor(ps, 32, 64);
      l += ps;

      // ---- pack P -> bf16 B-frags with cross-half exchange ----
      u32x4 pa[2];
#pragma unroll
      for (int s2 = 0; s2 < 2; ++s2) {
        const u32 A0 = pkbf(sa[8*s2+0], sa[8*s2+1]);
        const u32 A1 = pkbf(sa[8*s2+2], sa[8*s2+3]);
        const u32 B0 = pkbf(sa[8*s2+4], sa[8*s2+5]);
        const u32 B1 = pkbf(sa[8*s2+6], sa[8*s2+7]);
        const u32 sA0 = __shfl_xor(A0, 32, 64), sA1 = __shfl_xor(A1, 32, 64);
        const u32 sB0 = __shfl_xor(B0, 32, 64), sB1 = __shfl_xor(B1, 32, 64);
        pa[s2][0] = hx ? sB0 : A0;
        pa[s2][1] = hx ? sB1 : A1;
        pa[s2][2] = hx ? B0 : sA0;
        pa[s2][3] = hx ? B1 : sA1;
      }

      // ---- O^T += V^T * P^T ----
      __builtin_amdgcn_s_setprio(1);
#pragma unroll
      for (int s2 = 0; s2 < 2; ++s2) {
#pragma unroll
        for (int mb = 0; mb < 4; ++mb) {
          const int d0 = ln + 32 * mb;
          const int cb = (2 * s2 + hx) ^ (d0 & 3);
          bf16x8 vf = *(const bf16x8*)(vbp + d0 * KT + cb * 8);
          Oa[mb] = __builtin_amdgcn_mfma_f32_32x32x16_bf16(
              vf, __builtin_bit_cast(bf16x8, pa[s2]), Oa[mb], 0, 0, 0);
        }
      }
      __builtin_amdgcn_s_setprio(0);
    }

    __syncthreads();
    cur ^= 1;
  }

  // ---- epilogue: per-wave LDS transpose (8 KiB each), coalesced stores ----
  const float inv = 1.f / l;
  float* wlds = (float*)ldsraw + wv * 2048;
#pragma unroll
  for (int h2 = 0; h2 < 2; ++h2) {
#pragma unroll
    for (int mb2 = 0; mb2 < 2; ++mb2) {
      const int mb = 2 * h2 + mb2;
#pragma unroll
      for (int g2 = 0; g2 < 4; ++g2) {
        f32x4v v4;
        v4[0] = Oa[mb][4*g2+0] * inv; v4[1] = Oa[mb][4*g2+1] * inv;
        v4[2] = Oa[mb][4*g2+2] * inv; v4[3] = Oa[mb][4*g2+3] * inv;
        const int lslot = 2 * g2 + hx + 8 * mb2;
        const int pslot = lslot ^ (ln & 15);
        *(f32x4v*)(wlds + ln * 64 + pslot * 4) = v4;
      }
    }
    asm volatile("s_waitcnt lgkmcnt(0)" ::: "memory");
    __builtin_amdgcn_sched_barrier(0);
#pragma unroll
    for (int i = 0; i < 8; ++i) {
      const int q2 = 4 * i + (lane >> 4);
      const int lsl = lane & 15;
      const int psl = lsl ^ (q2 & 15);
      f32x4v v4 = *(const f32x4v*)(wlds + q2 * 64 + psl * 4);
      *(f32x4v*)(og + (size_t)(32 * wv + q2) * D + 64 * h2 + 4 * lsl) = v4;
    }
    __builtin_amdgcn_sched_barrier(0);
  }
}

// ---------------- fallback (round-2 kernel, used if ws too small) ----------
namespace fb {
typedef float f32x4 __attribute__((ext_vector_type(4)));
constexpr int QT2 = 128, KT2 = 64;
constexpr int KELEM = 64 * 128, VELEM = 128 * 64, BUFE = KELEM + VELEM;

__device__ __forceinline__ u32 bfb(float f) {
  u32 u = __float_as_uint(f);
  u += 0x7fffu + ((u >> 16) & 1u);
  return u >> 16;
}
__device__ __forceinline__ bf16_t f2bf(float f) {
  unsigned short hs = (unsigned short)bfb(f);
  bf16_t b; __builtin_memcpy(&b, &hs, 2); return b;
}

__global__ __launch_bounds__(256, 2)
void fa2(const float* __restrict__ qg_, const float* __restrict__ kg_,
         const float* __restrict__ vg_, float* __restrict__ og_)
{
  __shared__ __align__(16) char ldsraw[2 * BUFE * 2];
  bf16_t* lds = (bf16_t*)ldsraw;
  const int qt = (int)gridDim.x - 1 - (int)blockIdx.x;
  const int bh = blockIdx.y;
  const int b = bh >> 5, h = bh & 31, hk = h >> 2;
  const int tid = threadIdx.x;
  const int wv = tid >> 6, lane = tid & 63;
  const int ln = lane & 31, hx = lane >> 5;
  const int q0 = qt * QT2;
  const float* qg = qg_ + ((size_t)(b * HQ + h) * SQ + q0) * D;
  const float* kg = kg_ + (size_t)(b * HK + hk) * SQ * D;
  const float* vg = vg_ + (size_t)(b * HK + hk) * SQ * D;
  float*       og = og_ + ((size_t)(b * HQ + h) * SQ + q0) * D;
  const float qscale = 0.08838834764831845f * 1.4426950408889634f;
  bf16x8 qf[8];
  {
    const float* qrow = qg + (size_t)(32 * wv + ln) * D;
#pragma unroll
    for (int s = 0; s < 8; ++s) {
      const float* p = qrow + 16 * s + 8 * hx;
      f32x4 a = *(const f32x4*)p;
      f32x4 c = *(const f32x4*)(p + 4);
      bf16x8 t;
      t[0]=f2bf(a[0]*qscale); t[1]=f2bf(a[1]*qscale);
      t[2]=f2bf(a[2]*qscale); t[3]=f2bf(a[3]*qscale);
      t[4]=f2bf(c[0]*qscale); t[5]=f2bf(c[1]*qscale);
      t[6]=f2bf(c[2]*qscale); t[7]=f2bf(c[3]*qscale);
      qf[s] = t;
    }
  }
  f32x16 Oa[4];
#pragma unroll
  for (int mb = 0; mb < 4; ++mb)
#pragma unroll
    for (int r = 0; r < 16; ++r) Oa[mb][r] = 0.f;
  float m = -1e30f, l = 0.f;
  const int qrow_g = q0 + 32 * wv + ln;
  const int wlast = q0 + 32 * wv + 31;
  const int kv_end = q0 + QT2;
  const int krow = tid >> 2, kq = tid & 3;
  const int vkh = tid & 7, vd4 = tid >> 3;
  f32x4 kst[8], vst[8];
  auto kstage_load = [&](int kb) {
    const float* src = kg + (size_t)(kb + krow) * D + kq * 32;
#pragma unroll
    for (int it = 0; it < 4; ++it) {
      kst[2*it]   = *(const f32x4*)(src + 8 * it);
      kst[2*it+1] = *(const f32x4*)(src + 8 * it + 4);
    }
  };
  auto kstage_write = [&](int buf) {
    bf16_t* kbp = lds + buf * BUFE;
#pragma unroll
    for (int it = 0; it < 4; ++it) {
      const int cb = (kq * 4 + it) ^ (krow & 7);
      bf16x8 w;
      w[0]=f2bf(kst[2*it][0]);   w[1]=f2bf(kst[2*it][1]);
      w[2]=f2bf(kst[2*it][2]);   w[3]=f2bf(kst[2*it][3]);
      w[4]=f2bf(kst[2*it+1][0]); w[5]=f2bf(kst[2*it+1][1]);
      w[6]=f2bf(kst[2*it+1][2]); w[7]=f2bf(kst[2*it+1][3]);
      *(bf16x8*)(kbp + krow * 128 + cb * 8) = w;
    }
  };
  auto vstage_load = [&](int kb) {
    const float* src = vg + (size_t)(kb + 8 * vkh) * D + 4 * vd4;
#pragma unroll
    for (int i = 0; i < 8; ++i) vst[i] = *(const f32x4*)(src + (size_t)i * D);
  };
  auto vstage_write = [&](int buf) {
    bf16_t* vbp = lds + buf * BUFE + KELEM;
#pragma unroll
    for (int j = 0; j < 4; ++j) {
      const int d = 4 * vd4 + j;
      const int cb = vkh ^ (d & 7);
      bf16x8 w;
#pragma unroll
      for (int i = 0; i < 8; ++i) w[i] = f2bf(vst[i][j]);
      *(bf16x8*)(vbp + d * 64 + cb * 8) = w;
    }
  };
  kstage_load(0); kstage_write(0);
  vstage_load(0); vstage_write(0);
  __syncthreads();
  int cur = 0;
  for (int kb = 0; kb < kv_end; kb += KT2) {
    const bool nx = (kb + KT2 < kv_end);
    const bool act = (kb <= wlast);
    if (nx) kstage_load(kb + KT2);
    u32x4 pa[4];
    if (act) {
      const bf16_t* kbp = lds + cur * BUFE;
      f32x16 s0, s1;
#pragma unroll
      for (int r = 0; r < 16; ++r) { s0[r] = 0.f; s1[r] = 0.f; }
#pragma unroll
      for (int s = 0; s < 8; ++s) {
        const int cb = (2 * s + hx) ^ (ln & 7);
        bf16x8 k0 = *(const bf16x8*)(kbp + ln * 128 + cb * 8);
        bf16x8 k1 = *(const bf16x8*)(kbp + (ln + 32) * 128 + cb * 8);
        s0 = __builtin_amdgcn_mfma_f32_32x32x16_bf16(k0, qf[s], s0, 0, 0, 0);
        s1 = __builtin_amdgcn_mfma_f32_32x32x16_bf16(k1, qf[s], s1, 0, 0, 0);
      }
      if (kb + 63 > q0 + 32 * wv) {
#pragma unroll
        for (int r = 0; r < 16; ++r) {
          const int kl = (r & 3) + 8 * (r >> 2) + 4 * hx;
          if (kb + kl > qrow_g)      s0[r] = -1e30f;
          if (kb + 32 + kl > qrow_g) s1[r] = -1e30f;
        }
      }
      float tm = -1e30f;
#pragma unroll
      for (int r = 0; r < 16; ++r) tm = fmaxf(tm, fmaxf(s0[r], s1[r]));
      tm = fmaxf(tm, __shfl_xor(tm, 32, 64));
      if (__any(tm > m + 8.f)) {
        const float mn = fmaxf(m, tm);
        const float corr = fexp2(m - mn);
        m = mn; l *= corr;
#pragma unroll
        for (int mb = 0; mb < 4; ++mb)
#pragma unroll
          for (int r = 0; r < 16; ++r) Oa[mb][r] *= corr;
      }
      f32x16 p0, p1;
#pragma unroll
      for (int r = 0; r < 16; ++r) {
        p0[r] = fexp2(s0[r] - m);
        p1[r] = fexp2(s1[r] - m);
      }
      float ps = 0.f;
#pragma unroll
      for (int r = 0; r < 16; ++r) ps += p0[r] + p1[r];
      ps += __shfl_xor(ps, 32, 64);
      l += ps;
#pragma unroll
      for (int kb2 = 0; kb2 < 2; ++kb2) {
        const f32x16& pp = kb2 ? p1 : p0;
#pragma unroll
        for (int s2 = 0; s2 < 2; ++s2) {
          const u32 A0 = pkbf(pp[8*s2+0], pp[8*s2+1]);
          const u32 A1 = pkbf(pp[8*s2+2], pp[8*s2+3]);
          const u32 B0 = pkbf(pp[8*s2+4], pp[8*s2+5]);
          const u32 B1 = pkbf(pp[8*s2+6], pp[8*s2+7]);
          const u32 sA0 = __shfl_xor(A0, 32, 64), sA1 = __shfl_xor(A1, 32, 64);
          const u32 sB0 = __shfl_xor(B0, 32, 64), sB1 = __shfl_xor(B1, 32, 64);
          const int ks = 2 * kb2 + s2;
          pa[ks][0] = hx ? sB0 : A0;
          pa[ks][1] = hx ? sB1 : A1;
          pa[ks][2] = hx ? B0 : sA0;
          pa[ks][3] = hx ? B1 : sA1;
        }
      }
    }
    if (nx) kstage_write(cur ^ 1);
    if (nx) vstage_load(kb + KT2);
    if (act) {
      const bf16_t* vbp = lds + cur * BUFE + KELEM;
#pragma unroll
      for (int mb = 0; mb < 4; ++mb) {
        const int d0 = ln + 32 * mb;
#pragma unroll
        for (int ks = 0; ks < 4; ++ks) {
          const int cb = (hx + 2 * ks) ^ (d0 & 7);
          bf16x8 vf = *(const bf16x8*)(vbp + d0 * 64 + cb * 8);
          Oa[mb] = __builtin_amdgcn_mfma_f32_32x32x16_bf16(
              vf, __builtin_bit_cast(bf16x8, pa[ks]), Oa[mb], 0, 0, 0);
        }
      }
    }
    if (nx) vstage_write(cur ^ 1);
    __syncthreads();
    cur ^= 1;
  }
  float* ol = (float*)ldsraw;
  float* wbase = ol + wv * 4096;
  const float inv = 1.f / l;
#pragma unroll
  for (int mb = 0; mb < 4; ++mb) {
#pragma unroll
    for (int g = 0; g < 4; ++g) {
      f32x4 v4;
      v4[0] = Oa[mb][4*g+0]*inv; v4[1] = Oa[mb][4*g+1]*inv;
      v4[2] = Oa[mb][4*g+2]*inv; v4[3] = Oa[mb][4*g+3]*inv;
      const int chunk = (2 * g + hx + 8 * mb) ^ (ln & 7);
      *(f32x4*)(wbase + ln * 128 + chunk * 4) = v4;
    }
  }
  __syncthreads();
#pragma unroll
  for (int i = 0; i < 16; ++i) {
    const int q2 = 2 * i + hx;
    const int cs = ln ^ (q2 & 7);
    f32x4 v4 = *(const f32x4*)(wbase + q2 * 128 + cs * 4);
    *(f32x4*)(og + (size_t)(32 * wv + q2) * D + 4 * ln) = v4;
  }
}
}  // namespace fb

extern "C" void kernel_launch(void* const* d_in, const int* in_sizes, int n_in,
                              void* d_out, int out_size, void* d_ws, size_t ws_size,
                              hipStream_t stream) {
  const float* q = (const float*)d_in[0];
  const float* k = (const float*)d_in[1];
  const float* v = (const float*)d_in[2];
  float* out = (float*)d_out;
  if (ws_size >= WS_NEED) {
    prepass<<<dim3(B_ * HK * NT), 256, 0, stream>>>(k, v, (bf16_t*)d_ws);
    fa4<<<dim3(NQT * 64), 256, 0, stream>>>(q, (const bf16_t*)d_ws, out);
  } else {
    fb::fa2<<<dim3(SQ / fb::QT2, B_ * HQ), 256, 0, stream>>>(q, k, v, out);
  }
}